// Round 1
// baseline (1329.973 us; speedup 1.0000x reference)
//
#include <hip/hip_runtime.h>
#include <math.h>

#define B_    2
#define T_    128
#define D_    256
#define H_    8
#define F_    64
#define C_    512
#define TEMB_ 512

// ---------------------------------------------------------------------------
// Kernel 1: base[bt][c] = temb[bt][:] @ w_time[c][:]^T + b_time[c] + b_dist[c]
// BT=256 rows, C=512 cols, K=512. Tiny (67M MACs): 64 blocks, tiled.
// ---------------------------------------------------------------------------
__global__ __launch_bounds__(256) void k_base(
    const float* __restrict__ temb, const float* __restrict__ w_time,
    const float* __restrict__ b_time, const float* __restrict__ b_dist,
    float* __restrict__ base)
{
  __shared__ float tt[32][64];   // temb tile [bt_local][k]
  __shared__ float wt[64][65];   // w_time tile [c_local][k] (+1 pad)
  const int bt0 = blockIdx.x * 32;
  const int c0  = blockIdx.y * 64;
  const int tid = threadIdx.x;
  const int cl  = tid & 63;   // c lane
  const int g   = tid >> 6;   // bt group (0..3)
  float acc[8] = {0.f,0.f,0.f,0.f,0.f,0.f,0.f,0.f};

  for (int k0 = 0; k0 < TEMB_; k0 += 64) {
#pragma unroll
    for (int i = 0; i < 8; ++i) {          // 32x64 temb tile
      int idx = tid + i * 256;
      int r = idx >> 6, k = idx & 63;
      tt[r][k] = temb[(size_t)(bt0 + r) * TEMB_ + k0 + k];
    }
#pragma unroll
    for (int i = 0; i < 16; ++i) {         // 64x64 w_time tile
      int idx = tid + i * 256;
      int r = idx >> 6, k = idx & 63;
      wt[r][k] = w_time[(size_t)(c0 + r) * TEMB_ + k0 + k];
    }
    __syncthreads();
#pragma unroll
    for (int k = 0; k < 64; ++k) {
      float w = wt[cl][k];                 // lane-strided (65) -> 2-way, free
#pragma unroll
      for (int j = 0; j < 8; ++j)
        acc[j] += tt[g + 4 * j][k] * w;    // broadcast within wave
    }
    __syncthreads();
  }
  float bb = b_time[c0 + cl] + b_dist[c0 + cl];
#pragma unroll
  for (int j = 0; j < 8; ++j)
    base[(size_t)(bt0 + g + 4 * j) * C_ + c0 + cl] = acc[j] + bb;
}

// ---------------------------------------------------------------------------
// Kernel 2 (fused): one block per (b,t,h).
// Phase 1: R[s=128][f=64] = silu(base + dist.w_dist) @ w_out[h*64..][.]^T + b_out
//          K=512 in 8 c-tiles; silu tile + w_out tile staged in LDS;
//          per-thread 8s x 4f register accumulators, float4 LDS reads.
// Phase 2: out[d=256][s=128] = qk[d][f] . R[s][f]; qk staged 32 rows at a time;
//          per-thread 2s x 8d accumulators.
// LDS: 34816 + 17408 + 8192 + 1536 = 61952 B -> 2 blocks/CU.
// ---------------------------------------------------------------------------
__global__ __launch_bounds__(256) void k_main(
    const float* __restrict__ qk, const float* __restrict__ pd,
    const float* __restrict__ base, const float* __restrict__ w_dist,
    const float* __restrict__ w_out, const float* __restrict__ b_out,
    float* __restrict__ out)
{
  __shared__ __align__(16) float stile[T_][68];  // silu tile; later aliased as R[s][f]
  __shared__ __align__(16) float wtile[64][68];  // w_out tile [f][cc]
  __shared__ __align__(16) float qkt[32][64];    // qk tile [d_local][f]
  __shared__ float dfeat[3][T_];

  const int bx  = blockIdx.x;
  const int h   = bx & 7;
  const int t   = (bx >> 3) & 127;
  const int b   = bx >> 10;
  const int tid = threadIdx.x;

  // distance features for this (b,t): 3 x 128
  if (tid < T_) {
    float p = pd[((size_t)b * T_ + t) * T_ + tid];
    dfeat[0][tid] = log1pf(fmaxf(p, 0.f));
    dfeat[1][tid] = log1pf(fmaxf(-p, 0.f));
    dfeat[2][tid] = (p == 0.f) ? 1.f : 0.f;
  }

  const int fg   = tid & 15;  // phase-1 f group: f = fg + 16q
  const int sg   = tid >> 4;  // phase-1 s group: s = sg + 16i (0..15)
  const int c63  = tid & 63;  // silu lane (channel within tile)
  const int sgrp = tid >> 6;  // silu s group (0..3)

  float racc[8][4];
#pragma unroll
  for (int q = 0; q < 4; ++q) {
    float bo = b_out[h * 64 + fg + 16 * q];
#pragma unroll
    for (int i = 0; i < 8; ++i) racc[i][q] = bo;
  }

  const float* baserow = base + ((size_t)b * T_ + t) * C_;
  __syncthreads();  // dfeat ready

  for (int ct = 0; ct < 8; ++ct) {
    const int c0 = ct * 64;
    // stage w_out tile (64 rows o=h*64+f, 64 cols)
#pragma unroll
    for (int i = 0; i < 16; ++i) {
      int idx = tid + i * 256;
      int r = idx >> 6, cc = idx & 63;
      wtile[r][cc] = w_out[(size_t)(h * 64 + r) * C_ + c0 + cc];
    }
    // silu tile: stile[s][cc] for s=0..127, cc=0..63
    {
      float bc  = baserow[c0 + c63];
      float wd0 = w_dist[(c0 + c63) * 3 + 0];
      float wd1 = w_dist[(c0 + c63) * 3 + 1];
      float wd2 = w_dist[(c0 + c63) * 3 + 2];
#pragma unroll
      for (int j = 0; j < 32; ++j) {
        int s = sgrp + 4 * j;
        float x = bc + dfeat[0][s] * wd0 + dfeat[1][s] * wd1 + dfeat[2][s] * wd2;
        stile[s][c63] = x / (1.f + __expf(-x));  // silu
      }
    }
    __syncthreads();
    // accumulate: racc[i][q] += stile[sg+16i][cc] * wtile[fg+16q][cc]
#pragma unroll
    for (int cc0 = 0; cc0 < 64; cc0 += 4) {
      float4 wv[4], sv[8];
#pragma unroll
      for (int q = 0; q < 4; ++q)
        wv[q] = *reinterpret_cast<const float4*>(&wtile[fg + 16 * q][cc0]);
#pragma unroll
      for (int i = 0; i < 8; ++i)
        sv[i] = *reinterpret_cast<const float4*>(&stile[sg + 16 * i][cc0]);
#pragma unroll
      for (int i = 0; i < 8; ++i)
#pragma unroll
        for (int q = 0; q < 4; ++q)
          racc[i][q] += sv[i].x * wv[q].x + sv[i].y * wv[q].y +
                        sv[i].z * wv[q].z + sv[i].w * wv[q].w;
    }
    __syncthreads();
  }

  // stash R into stile (alias): R[s][f]
#pragma unroll
  for (int i = 0; i < 8; ++i)
#pragma unroll
    for (int q = 0; q < 4; ++q)
      stile[sg + 16 * i][fg + 16 * q] = racc[i][q];
  __syncthreads();

  // Phase 2: out[d][s] = sum_f qk[d][f] * R[s][f]
  const int sl = tid & 63;   // s lane
  const int wg = tid >> 6;   // 0..3 -> d = d0 + wg + 4*dj
  const size_t HTF = (size_t)H_ * T_ * F_;
  const size_t HTT = (size_t)H_ * T_ * T_;
  const float* qkb = qk + (size_t)b * D_ * HTF + (size_t)h * T_ * F_ + (size_t)t * F_;
  float* outb = out + (size_t)b * D_ * HTT + (size_t)h * T_ * T_ + (size_t)t * T_;

  for (int d0 = 0; d0 < D_; d0 += 32) {
    {   // stage qk rows d0..d0+31 (each 64 floats)
      int r  = tid >> 3;
      int fo = (tid & 7) * 8;
      const float* src = qkb + (size_t)(d0 + r) * HTF + fo;
      *reinterpret_cast<float4*>(&qkt[r][fo])     = *reinterpret_cast<const float4*>(src);
      *reinterpret_cast<float4*>(&qkt[r][fo + 4]) = *reinterpret_cast<const float4*>(src + 4);
    }
    __syncthreads();
    float acc0[8], acc1[8];
#pragma unroll
    for (int dj = 0; dj < 8; ++dj) { acc0[dj] = 0.f; acc1[dj] = 0.f; }
#pragma unroll
    for (int k0 = 0; k0 < 64; k0 += 4) {
      float4 rv0 = *reinterpret_cast<const float4*>(&stile[sl][k0]);
      float4 rv1 = *reinterpret_cast<const float4*>(&stile[sl + 64][k0]);
#pragma unroll
      for (int dj = 0; dj < 8; ++dj) {
        float4 qv = *reinterpret_cast<const float4*>(&qkt[wg + 4 * dj][k0]); // broadcast
        acc0[dj] += rv0.x * qv.x + rv0.y * qv.y + rv0.z * qv.z + rv0.w * qv.w;
        acc1[dj] += rv1.x * qv.x + rv1.y * qv.y + rv1.z * qv.z + rv1.w * qv.w;
      }
    }
#pragma unroll
    for (int dj = 0; dj < 8; ++dj) {
      int d = d0 + wg + 4 * dj;
      outb[(size_t)d * HTT + sl]      = acc0[dj];
      outb[(size_t)d * HTT + 64 + sl] = acc1[dj];
    }
    __syncthreads();
  }
}

extern "C" void kernel_launch(void* const* d_in, const int* in_sizes, int n_in,
                              void* d_out, int out_size, void* d_ws, size_t ws_size,
                              hipStream_t stream) {
  const float* qk     = (const float*)d_in[0];
  const float* pd     = (const float*)d_in[1];
  const float* temb   = (const float*)d_in[2];
  const float* w_dist = (const float*)d_in[3];
  const float* b_dist = (const float*)d_in[4];
  const float* w_time = (const float*)d_in[5];
  const float* b_time = (const float*)d_in[6];
  const float* w_out  = (const float*)d_in[7];
  const float* b_out  = (const float*)d_in[8];
  float* out  = (float*)d_out;
  float* base = (float*)d_ws;   // B*T*C floats = 512 KB scratch

  hipLaunchKernelGGL(k_base, dim3(8, 8), dim3(256), 0, stream,
                     temb, w_time, b_time, b_dist, base);
  hipLaunchKernelGGL(k_main, dim3(B_ * T_ * H_), dim3(256), 0, stream,
                     qk, pd, base, w_dist, w_out, b_out, out);
}

// Round 2
// 195.235 us; speedup vs baseline: 6.8122x; 6.8122x over previous
//
#include <hip/hip_runtime.h>
#include <hip/hip_bf16.h>
#include <math.h>

typedef __attribute__((ext_vector_type(8))) short short8;
typedef __attribute__((ext_vector_type(4))) float f32x4;

#define B_    2
#define T_    128
#define D_    256
#define H_    8
#define F_    64
#define C_    512
#define TEMB_ 512

static __device__ __forceinline__ unsigned short f2bf(float f) {
  __hip_bfloat16 h = __float2bfloat16(f);
  return reinterpret_cast<unsigned short&>(h);
}
static __device__ __forceinline__ unsigned int pk2(float a, float b) {
  return (unsigned int)f2bf(a) | ((unsigned int)f2bf(b) << 16);
}

// ---------------------------------------------------------------------------
// k_prep: w_out (fp32 [512][512]) -> wsw (bf16, MFMA-B-fragment order:
// slot[(oi*16+kjg)*64+lane] holds 8 bf16 at o=oi*16+(lane&15),
// c=kjg*32+(lane>>4)*8 .. +8).  Also pad w_dist [512][3] -> wd4 [512][4].
// ---------------------------------------------------------------------------
__global__ __launch_bounds__(256) void k_prep(
    const float* __restrict__ w_out, const float* __restrict__ w_dist,
    short* __restrict__ wsw, float* __restrict__ wd4)
{
  int gid = blockIdx.x * 256 + threadIdx.x;
  for (int s = gid; s < 32768; s += 16384) {
    int oi = s >> 10, rem = s & 1023, kjg = rem >> 6, l = rem & 63;
    int o = oi * 16 + (l & 15), c = kjg * 32 + (l >> 4) * 8;
    const float* src = w_out + (size_t)o * C_ + c;
    float4 a = *reinterpret_cast<const float4*>(src);
    float4 b = *reinterpret_cast<const float4*>(src + 4);
    uint4 v; v.x = pk2(a.x, a.y); v.y = pk2(a.z, a.w);
    v.z = pk2(b.x, b.y); v.w = pk2(b.z, b.w);
    *reinterpret_cast<uint4*>(wsw + (size_t)s * 8) = v;
  }
  if (gid < C_) {
    wd4[gid * 4 + 0] = w_dist[gid * 3 + 0];
    wd4[gid * 4 + 1] = w_dist[gid * 3 + 1];
    wd4[gid * 4 + 2] = w_dist[gid * 3 + 2];
    wd4[gid * 4 + 3] = 0.f;
  }
}

// ---------------------------------------------------------------------------
// k_base: base[bt][c] = temb @ w_time^T + b_time + b_dist   (verified R1)
// ---------------------------------------------------------------------------
__global__ __launch_bounds__(256) void k_base(
    const float* __restrict__ temb, const float* __restrict__ w_time,
    const float* __restrict__ b_time, const float* __restrict__ b_dist,
    float* __restrict__ base)
{
  __shared__ float tt[32][64];
  __shared__ float wt[64][65];
  const int bt0 = blockIdx.x * 32;
  const int c0  = blockIdx.y * 64;
  const int tid = threadIdx.x;
  const int cl  = tid & 63;
  const int g   = tid >> 6;
  float acc[8] = {0.f,0.f,0.f,0.f,0.f,0.f,0.f,0.f};

  for (int k0 = 0; k0 < TEMB_; k0 += 64) {
#pragma unroll
    for (int i = 0; i < 8; ++i) {
      int idx = tid + i * 256; int r = idx >> 6, k = idx & 63;
      tt[r][k] = temb[(size_t)(bt0 + r) * TEMB_ + k0 + k];
    }
#pragma unroll
    for (int i = 0; i < 16; ++i) {
      int idx = tid + i * 256; int r = idx >> 6, k = idx & 63;
      wt[r][k] = w_time[(size_t)(c0 + r) * TEMB_ + k0 + k];
    }
    __syncthreads();
#pragma unroll
    for (int k = 0; k < 64; ++k) {
      float w = wt[cl][k];
#pragma unroll
      for (int j = 0; j < 8; ++j) acc[j] += tt[g + 4 * j][k] * w;
    }
    __syncthreads();
  }
  float bb = b_time[c0 + cl] + b_dist[c0 + cl];
#pragma unroll
  for (int j = 0; j < 8; ++j)
    base[(size_t)(bt0 + g + 4 * j) * C_ + c0 + cl] = acc[j] + bb;
}

// ---------------------------------------------------------------------------
// k_rpe: per block (bt, o-half): R[s=128][o=256] = silu(emb) @ w_out^T + b_out
// MFMA 16x16x32 bf16, K=512 in 8 k-tiles of 64.  Silu tile produced directly
// into A-fragment LDS layout.  4 waves, wave tile 64(M) x 128(N).
// ---------------------------------------------------------------------------
__global__ __launch_bounds__(256, 2) void k_rpe(
    const float* __restrict__ pd, const float* __restrict__ base,
    const float* __restrict__ wd4, const short* __restrict__ wsw,
    const float* __restrict__ b_out, unsigned short* __restrict__ R)
{
  __shared__ __align__(16) short At[8192];    // 16 KB: [si(8)][kj(2)][lane(64)][8]
  __shared__ __align__(16) short Bt[16384];   // 32 KB: [oi_l(16)][kj(2)][lane(64)][8]
  __shared__ float df[3][T_];

  const int bx   = blockIdx.x;
  const int bt   = bx >> 1;
  const int half = bx & 1;
  const int b    = bt >> 7;
  const int t    = bt & 127;
  const int tid  = threadIdx.x;
  const int lane = tid & 63;
  const int wave = tid >> 6;
  const int wm   = wave >> 1;     // 0..1  (M half)
  const int wn   = wave & 1;      // 0..1  (N half)
  const int lanem = lane & 15;
  const int laneg = lane >> 4;

  if (tid < T_) {
    float p = pd[((size_t)b * T_ + t) * T_ + tid];
    df[0][tid] = log1pf(fmaxf(p, 0.f));
    df[1][tid] = log1pf(fmaxf(-p, 0.f));
    df[2][tid] = (p == 0.f) ? 1.f : 0.f;
  }

  // producer thread mapping
  const int s_low = tid & 15;
  const int cg    = (tid >> 4) & 7;      // c-group within k-tile (8 c each)
  const int si_b  = (tid >> 7) * 4;      // si base (0 or 4)
  const int kjA   = cg >> 2;
  const int kgrp  = cg & 3;
  const int laneslotA = s_low + 16 * kgrp;
  const float* baserow = base + (size_t)bt * C_;

  f32x4 acc[4][8];
#pragma unroll
  for (int mi = 0; mi < 4; ++mi)
#pragma unroll
    for (int ni = 0; ni < 8; ++ni) acc[mi][ni] = (f32x4){0.f, 0.f, 0.f, 0.f};

  for (int kt = 0; kt < 8; ++kt) {
    __syncthreads();   // prev-iter consumers done (covers df on first iter)
    // ---- stage B tile (reg-staged copy of pre-swizzled w_out) ----
#pragma unroll
    for (int i = 0; i < 8; ++i) {
      int idx  = i * 256 + tid;
      int oi_l = idx >> 7, kj = (idx >> 6) & 1, l = idx & 63;
      int gslot = ((half * 16 + oi_l) * 16 + kt * 2 + kj) * 64 + l;
      uint4 v = *reinterpret_cast<const uint4*>(wsw + (size_t)gslot * 8);
      *reinterpret_cast<uint4*>(&Bt[idx * 8]) = v;
    }
    // ---- produce A tile: silu(base + df.wd) in fragment layout ----
    {
      const int cglob = kt * 64 + cg * 8;
      float4 b0 = *reinterpret_cast<const float4*>(baserow + cglob);
      float4 b1 = *reinterpret_cast<const float4*>(baserow + cglob + 4);
      float bs[8] = {b0.x, b0.y, b0.z, b0.w, b1.x, b1.y, b1.z, b1.w};
      float4 w[8];
#pragma unroll
      for (int j = 0; j < 8; ++j)
        w[j] = *reinterpret_cast<const float4*>(wd4 + (size_t)(cglob + j) * 4);
#pragma unroll
      for (int q = 0; q < 4; ++q) {
        int si = si_b + q;
        int s  = si * 16 + s_low;
        float d0 = df[0][s], d1 = df[1][s], d2 = df[2][s];
        float sl[8];
#pragma unroll
        for (int j = 0; j < 8; ++j) {
          float x = bs[j] + d0 * w[j].x + d1 * w[j].y + d2 * w[j].z;
          sl[j] = x / (1.f + __expf(-x));
        }
        uint4 v; v.x = pk2(sl[0], sl[1]); v.y = pk2(sl[2], sl[3]);
        v.z = pk2(sl[4], sl[5]); v.w = pk2(sl[6], sl[7]);
        *reinterpret_cast<uint4*>(&At[((si * 2 + kjA) * 64 + laneslotA) * 8]) = v;
      }
    }
    __syncthreads();
    // ---- MFMA ----
#pragma unroll
    for (int kj = 0; kj < 2; ++kj) {
      short8 a[4];
#pragma unroll
      for (int mi = 0; mi < 4; ++mi)
        a[mi] = *reinterpret_cast<const short8*>(
            &At[(((wm * 4 + mi) * 2 + kj) * 64 + lane) * 8]);
#pragma unroll
      for (int ni = 0; ni < 8; ++ni) {
        short8 bb = *reinterpret_cast<const short8*>(
            &Bt[(((wn * 8 + ni) * 2 + kj) * 64 + lane) * 8]);
#pragma unroll
        for (int mi = 0; mi < 4; ++mi)
          acc[mi][ni] = __builtin_amdgcn_mfma_f32_16x16x32_bf16(
              a[mi], bb, acc[mi][ni], 0, 0, 0);
      }
    }
  }
  // ---- epilogue: + b_out, cvt bf16, store R[bt][s][o] ----
  const int o_base = half * 256 + wn * 128;
#pragma unroll
  for (int ni = 0; ni < 8; ++ni) {
    int o = o_base + ni * 16 + lanem;
    float bo = b_out[o];
#pragma unroll
    for (int mi = 0; mi < 4; ++mi) {
      int s0 = wm * 64 + mi * 16 + laneg * 4;
#pragma unroll
      for (int reg = 0; reg < 4; ++reg)
        R[((size_t)bt * T_ + s0 + reg) * C_ + o] = f2bf(acc[mi][ni][reg] + bo);
    }
  }
}

// ---------------------------------------------------------------------------
// k_qkr: per block (b,h,t): out[d=256][s=128] = qk[d][f] . R[s][f], K=64.
// A-frags (qk, fp32->bf16) and B-frags (R, bf16) loaded straight to registers.
// 4 waves, each 64(d) x 128(s).
// ---------------------------------------------------------------------------
__global__ __launch_bounds__(256, 2) void k_qkr(
    const float* __restrict__ qk, const unsigned short* __restrict__ R,
    float* __restrict__ out)
{
  const int bx = blockIdx.x;
  const int h  = bx & 7;
  const int t  = (bx >> 3) & 127;
  const int b  = bx >> 10;
  const int bt = b * T_ + t;
  const int tid  = threadIdx.x;
  const int lane = tid & 63;
  const int wave = tid >> 6;
  const int lanem = lane & 15;
  const int laneg = lane >> 4;
  const int d0w = wave * 64;

  // qk[b][d][h][t][f]: base for (b,h,t), row stride (d) = H*T*F = 65536
  const float* qkb = qk + (size_t)b * D_ * H_ * T_ * F_
                        + (size_t)h * T_ * F_ + (size_t)t * F_;
  const unsigned short* Rb = R + (size_t)bt * T_ * C_ + h * F_;

  f32x4 acc[4][8];
#pragma unroll
  for (int mi = 0; mi < 4; ++mi)
#pragma unroll
    for (int ni = 0; ni < 8; ++ni) acc[mi][ni] = (f32x4){0.f, 0.f, 0.f, 0.f};

#pragma unroll
  for (int kj = 0; kj < 2; ++kj) {
    const int f0 = kj * 32 + laneg * 8;
    short8 a[4];
#pragma unroll
    for (int mi = 0; mi < 4; ++mi) {
      const float* src = qkb + (size_t)(d0w + mi * 16 + lanem) * (H_ * T_ * F_) + f0;
      float4 q0 = *reinterpret_cast<const float4*>(src);
      float4 q1 = *reinterpret_cast<const float4*>(src + 4);
      union { uint4 u; short8 s; } cv;
      cv.u.x = pk2(q0.x, q0.y); cv.u.y = pk2(q0.z, q0.w);
      cv.u.z = pk2(q1.x, q1.y); cv.u.w = pk2(q1.z, q1.w);
      a[mi] = cv.s;
    }
#pragma unroll
    for (int ni = 0; ni < 8; ++ni) {
      short8 bb = *reinterpret_cast<const short8*>(
          Rb + (size_t)(ni * 16 + lanem) * C_ + f0);
#pragma unroll
      for (int mi = 0; mi < 4; ++mi)
        acc[mi][ni] = __builtin_amdgcn_mfma_f32_16x16x32_bf16(
            a[mi], bb, acc[mi][ni], 0, 0, 0);
    }
  }

  // out[b][d][h][t][s]: d stride = H*T*T = 131072
  float* outb = out + (size_t)b * D_ * H_ * T_ * T_
                    + (size_t)h * T_ * T_ + (size_t)t * T_;
#pragma unroll
  for (int mi = 0; mi < 4; ++mi) {
#pragma unroll
    for (int reg = 0; reg < 4; ++reg) {
      int d = d0w + mi * 16 + laneg * 4 + reg;
      float* row = outb + (size_t)d * (H_ * T_ * T_);
#pragma unroll
      for (int ni = 0; ni < 8; ++ni)
        row[ni * 16 + lanem] = acc[mi][ni][reg];
    }
  }
}

extern "C" void kernel_launch(void* const* d_in, const int* in_sizes, int n_in,
                              void* d_out, int out_size, void* d_ws, size_t ws_size,
                              hipStream_t stream) {
  const float* qk     = (const float*)d_in[0];
  const float* pd     = (const float*)d_in[1];
  const float* temb   = (const float*)d_in[2];
  const float* w_dist = (const float*)d_in[3];
  const float* b_dist = (const float*)d_in[4];
  const float* w_time = (const float*)d_in[5];
  const float* b_time = (const float*)d_in[6];
  const float* w_out  = (const float*)d_in[7];
  const float* b_out  = (const float*)d_in[8];
  float* out = (float*)d_out;

  char* ws = (char*)d_ws;
  float* base          = (float*)(ws);                 // 524288 B
  float* wd4           = (float*)(ws + 524288);        //   8192 B
  short* wsw           = (short*)(ws + 532480);        // 524288 B
  unsigned short* Rbuf = (unsigned short*)(ws + 1056768); // 33554432 B

  hipLaunchKernelGGL(k_prep, dim3(64), dim3(256), 0, stream,
                     w_out, w_dist, wsw, wd4);
  hipLaunchKernelGGL(k_base, dim3(8, 8), dim3(256), 0, stream,
                     temb, w_time, b_time, b_dist, base);
  hipLaunchKernelGGL(k_rpe, dim3(512), dim3(256), 0, stream,
                     pd, base, wd4, wsw, b_out, Rbuf);
  hipLaunchKernelGGL(k_qkr, dim3(B_ * T_ * H_), dim3(256), 0, stream,
                     qk, Rbuf, out);
}

// Round 3
// 174.709 us; speedup vs baseline: 7.6125x; 1.1175x over previous
//
#include <hip/hip_runtime.h>
#include <hip/hip_bf16.h>
#include <math.h>

typedef __attribute__((ext_vector_type(8))) short short8;
typedef __attribute__((ext_vector_type(4))) float f32x4;

#define B_    2
#define T_    128
#define D_    256
#define H_    8
#define F_    64
#define C_    512
#define TEMB_ 512

static __device__ __forceinline__ unsigned short f2bf(float f) {
  __hip_bfloat16 h = __float2bfloat16(f);
  return reinterpret_cast<unsigned short&>(h);
}
static __device__ __forceinline__ unsigned int pk2(float a, float b) {
  return (unsigned int)f2bf(a) | ((unsigned int)f2bf(b) << 16);
}

// ---------------------------------------------------------------------------
// k_prep: w_out fp32 [512][512] -> wsw bf16 in MFMA-B-fragment order:
// slot (oi*16+kjg)*64+lane holds 8 bf16 at o=oi*16+(lane&15),
// c=kjg*32+(lane>>4)*8.. ; also pad w_dist [512][3] -> wd4 [512][4].
// ---------------------------------------------------------------------------
__global__ __launch_bounds__(256) void k_prep(
    const float* __restrict__ w_out, const float* __restrict__ w_dist,
    short* __restrict__ wsw, float* __restrict__ wd4)
{
  int gid = blockIdx.x * 256 + threadIdx.x;
  for (int s = gid; s < 32768; s += 16384) {
    int oi = s >> 10, rem = s & 1023, kjg = rem >> 6, l = rem & 63;
    int o = oi * 16 + (l & 15), c = kjg * 32 + (l >> 4) * 8;
    const float* src = w_out + (size_t)o * C_ + c;
    float4 a = *reinterpret_cast<const float4*>(src);
    float4 b = *reinterpret_cast<const float4*>(src + 4);
    uint4 v; v.x = pk2(a.x, a.y); v.y = pk2(a.z, a.w);
    v.z = pk2(b.x, b.y); v.w = pk2(b.z, b.w);
    *reinterpret_cast<uint4*>(wsw + (size_t)s * 8) = v;
  }
  if (gid < C_) {
    wd4[gid * 4 + 0] = w_dist[gid * 3 + 0];
    wd4[gid * 4 + 1] = w_dist[gid * 3 + 1];
    wd4[gid * 4 + 2] = w_dist[gid * 3 + 2];
    wd4[gid * 4 + 3] = 0.f;
  }
}

// ---------------------------------------------------------------------------
// k_base: base[bt][c] = temb @ w_time^T + b_time + b_dist   (verified R1/R2)
// ---------------------------------------------------------------------------
__global__ __launch_bounds__(256) void k_base(
    const float* __restrict__ temb, const float* __restrict__ w_time,
    const float* __restrict__ b_time, const float* __restrict__ b_dist,
    float* __restrict__ base)
{
  __shared__ float tt[32][64];
  __shared__ float wt[64][65];
  const int bt0 = blockIdx.x * 32;
  const int c0  = blockIdx.y * 64;
  const int tid = threadIdx.x;
  const int cl  = tid & 63;
  const int g   = tid >> 6;
  float acc[8] = {0.f,0.f,0.f,0.f,0.f,0.f,0.f,0.f};

  for (int k0 = 0; k0 < TEMB_; k0 += 64) {
#pragma unroll
    for (int i = 0; i < 8; ++i) {
      int idx = tid + i * 256; int r = idx >> 6, k = idx & 63;
      tt[r][k] = temb[(size_t)(bt0 + r) * TEMB_ + k0 + k];
    }
#pragma unroll
    for (int i = 0; i < 16; ++i) {
      int idx = tid + i * 256; int r = idx >> 6, k = idx & 63;
      wt[r][k] = w_time[(size_t)(c0 + r) * TEMB_ + k0 + k];
    }
    __syncthreads();
#pragma unroll
    for (int k = 0; k < 64; ++k) {
      float w = wt[cl][k];
#pragma unroll
      for (int j = 0; j < 8; ++j) acc[j] += tt[g + 4 * j][k] * w;
    }
    __syncthreads();
  }
  float bb = b_time[c0 + cl] + b_dist[c0 + cl];
#pragma unroll
  for (int j = 0; j < 8; ++j)
    base[(size_t)(bt0 + g + 4 * j) * C_ + c0 + cl] = acc[j] + bb;
}

// ---------------------------------------------------------------------------
// k_fused: one block per (b,t), 512 threads (8 waves), 149 KB LDS.
// Phase 1: R[s=128][o=512] = silu(base + df.wd) @ w_out^T + b_out, K=512,
//          MFMA 16x16x32 bf16; waves as 2(M) x 4(N); B-frags direct from
//          global wsw (L2); R written to LDS bf16, XOR-swizzled per 16B
//          granule: g' = (g&~7) | ((g^s)&7).
// Phase 2: wave = h; out[d=256][s=128] = qk[d][f] . R[s][h*64+f];
//          R B-frags resident in 64 VGPRs, qk A-frags double-buffered
//          (32-d chunks, 8 chunks, 1-deep prefetch).
// ---------------------------------------------------------------------------
__global__ __launch_bounds__(512, 2) void k_fused(
    const float* __restrict__ qk, const float* __restrict__ pd,
    const float* __restrict__ base, const float* __restrict__ wd4,
    const short* __restrict__ wsw, const float* __restrict__ b_out,
    float* __restrict__ out)
{
  __shared__ __align__(16) unsigned short Rlds[T_ * C_];  // 128 KB swizzled [s][o]
  __shared__ __align__(16) short At[8192];                // 16 KB A-frag tile
  __shared__ float df[3][T_];

  const int bt = blockIdx.x;
  const int b  = bt >> 7;
  const int t  = bt & 127;
  const int tid  = threadIdx.x;
  const int lane = tid & 63;
  const int wave = tid >> 6;          // 0..7
  const int lanem = lane & 15;
  const int laneg = lane >> 4;

  if (tid < T_) {
    float p = pd[((size_t)b * T_ + t) * T_ + tid];
    df[0][tid] = log1pf(fmaxf(p, 0.f));
    df[1][tid] = log1pf(fmaxf(-p, 0.f));
    df[2][tid] = (p == 0.f) ? 1.f : 0.f;
  }

  // ---------------- Phase 1 ----------------
  const int wm = wave >> 2;           // 0..1  s-half
  const int wn = wave & 3;            // 0..3  o-quarter

  // A-tile producer mapping (512 threads -> 2 s x 8 c each per k-tile)
  const int s_low = tid & 15;
  const int cg    = (tid >> 4) & 7;   // c-group (8 c each)
  const int si_b  = (tid >> 7) * 2;   // 0,2,4,6
  const int kjA   = cg >> 2;
  const int cgl   = cg & 3;
  const int laneslotA = s_low + 16 * cgl;
  const float* baserow = base + (size_t)bt * C_;

  f32x4 acc[4][8];
#pragma unroll
  for (int mi = 0; mi < 4; ++mi)
#pragma unroll
    for (int ni = 0; ni < 8; ++ni) acc[mi][ni] = (f32x4){0.f, 0.f, 0.f, 0.f};

  for (int kt = 0; kt < 8; ++kt) {
    __syncthreads();   // prev-iter At consumers done (covers df on kt=0)
    short8 b0[8], b1[8];
    const int kjg0 = kt * 2, kjg1 = kt * 2 + 1;
#pragma unroll
    for (int ni = 0; ni < 8; ++ni)     // issue kj=0 B-frag loads early (L2)
      b0[ni] = *reinterpret_cast<const short8*>(
          wsw + ((size_t)((wn * 8 + ni) * 16 + kjg0) * 64 + lane) * 8);
    // ---- produce A tile: silu(base + df.wd) in fragment layout ----
    {
      const int cglob = kt * 64 + cg * 8;
      float4 bv0 = *reinterpret_cast<const float4*>(baserow + cglob);
      float4 bv1 = *reinterpret_cast<const float4*>(baserow + cglob + 4);
      float bs[8] = {bv0.x, bv0.y, bv0.z, bv0.w, bv1.x, bv1.y, bv1.z, bv1.w};
      float4 w[8];
#pragma unroll
      for (int j = 0; j < 8; ++j)
        w[j] = *reinterpret_cast<const float4*>(wd4 + (size_t)(cglob + j) * 4);
#pragma unroll
      for (int q = 0; q < 2; ++q) {
        int si = si_b + q;
        int s  = si * 16 + s_low;
        float d0 = df[0][s], d1 = df[1][s], d2 = df[2][s];
        float sl[8];
#pragma unroll
        for (int j = 0; j < 8; ++j) {
          float x = bs[j] + d0 * w[j].x + d1 * w[j].y + d2 * w[j].z;
          sl[j] = x / (1.f + __expf(-x));
        }
        uint4 v; v.x = pk2(sl[0], sl[1]); v.y = pk2(sl[2], sl[3]);
        v.z = pk2(sl[4], sl[5]); v.w = pk2(sl[6], sl[7]);
        *reinterpret_cast<uint4*>(&At[((si * 2 + kjA) * 64 + laneslotA) * 8]) = v;
      }
    }
#pragma unroll
    for (int ni = 0; ni < 8; ++ni)     // kj=1 B-frag loads overlap the barrier
      b1[ni] = *reinterpret_cast<const short8*>(
          wsw + ((size_t)((wn * 8 + ni) * 16 + kjg1) * 64 + lane) * 8);
    __syncthreads();
    // ---- MFMA ----
    short8 a0[4], a1[4];
#pragma unroll
    for (int mi = 0; mi < 4; ++mi)
      a0[mi] = *reinterpret_cast<const short8*>(
          &At[(((wm * 4 + mi) * 2 + 0) * 64 + lane) * 8]);
#pragma unroll
    for (int ni = 0; ni < 8; ++ni)
#pragma unroll
      for (int mi = 0; mi < 4; ++mi)
        acc[mi][ni] = __builtin_amdgcn_mfma_f32_16x16x32_bf16(
            a0[mi], b0[ni], acc[mi][ni], 0, 0, 0);
#pragma unroll
    for (int mi = 0; mi < 4; ++mi)
      a1[mi] = *reinterpret_cast<const short8*>(
          &At[(((wm * 4 + mi) * 2 + 1) * 64 + lane) * 8]);
#pragma unroll
    for (int ni = 0; ni < 8; ++ni)
#pragma unroll
      for (int mi = 0; mi < 4; ++mi)
        acc[mi][ni] = __builtin_amdgcn_mfma_f32_16x16x32_bf16(
            a1[mi], b1[ni], acc[mi][ni], 0, 0, 0);
  }

  // ---- epilogue: + b_out, bf16, swizzled store into Rlds ----
#pragma unroll
  for (int ni = 0; ni < 8; ++ni) {
    const int o  = wn * 128 + ni * 16 + lanem;
    const float bo = b_out[o];
    const int g  = o >> 3;
#pragma unroll
    for (int mi = 0; mi < 4; ++mi) {
#pragma unroll
      for (int reg = 0; reg < 4; ++reg) {
        int s  = wm * 64 + mi * 16 + laneg * 4 + reg;
        int gp = (g & ~7) | ((g ^ s) & 7);
        Rlds[s * 512 + gp * 8 + (o & 7)] = f2bf(acc[mi][ni][reg] + bo);
      }
    }
  }
  __syncthreads();

  // ---------------- Phase 2: wave = h ----------------
  const int h = wave;
  short8 brf[2][8];                    // R B-frags, resident across d-loop
#pragma unroll
  for (int kj = 0; kj < 2; ++kj)
#pragma unroll
    for (int ni = 0; ni < 8; ++ni) {
      int s  = ni * 16 + lanem;
      int g  = h * 8 + kj * 4 + laneg;
      int gp = (g & ~7) | ((g ^ s) & 7);
      brf[kj][ni] = *reinterpret_cast<const short8*>(&Rlds[s * 512 + gp * 8]);
    }

  const int HTF = H_ * T_ * F_;        // 65536
  const int HTT = H_ * T_ * T_;        // 131072
  const float* qkb = qk + (size_t)b * D_ * HTF + (size_t)h * T_ * F_ + (size_t)t * F_;
  float* outb = out + (size_t)b * D_ * HTT + (size_t)h * T_ * T_ + (size_t)t * T_;

  auto LOADC = [&](int d0, float4* buf) {
#pragma unroll
    for (int mi = 0; mi < 2; ++mi) {
      const float* src = qkb + (size_t)(d0 + mi * 16 + lanem) * HTF + laneg * 8;
      buf[mi * 4 + 0] = *reinterpret_cast<const float4*>(src);
      buf[mi * 4 + 1] = *reinterpret_cast<const float4*>(src + 4);
      buf[mi * 4 + 2] = *reinterpret_cast<const float4*>(src + 32);
      buf[mi * 4 + 3] = *reinterpret_cast<const float4*>(src + 36);
    }
  };
  auto COMP = [&](int d0, const float4* buf) {
    f32x4 ac[2][8];
#pragma unroll
    for (int mi = 0; mi < 2; ++mi)
#pragma unroll
      for (int ni = 0; ni < 8; ++ni) ac[mi][ni] = (f32x4){0.f, 0.f, 0.f, 0.f};
#pragma unroll
    for (int kj = 0; kj < 2; ++kj) {
      short8 av[2];
#pragma unroll
      for (int mi = 0; mi < 2; ++mi) {
        float4 p0 = buf[mi * 4 + kj * 2], p1 = buf[mi * 4 + kj * 2 + 1];
        union { uint4 u; short8 s; } cv;
        cv.u.x = pk2(p0.x, p0.y); cv.u.y = pk2(p0.z, p0.w);
        cv.u.z = pk2(p1.x, p1.y); cv.u.w = pk2(p1.z, p1.w);
        av[mi] = cv.s;
      }
#pragma unroll
      for (int ni = 0; ni < 8; ++ni)
#pragma unroll
        for (int mi = 0; mi < 2; ++mi)
          ac[mi][ni] = __builtin_amdgcn_mfma_f32_16x16x32_bf16(
              av[mi], brf[kj][ni], ac[mi][ni], 0, 0, 0);
    }
#pragma unroll
    for (int mi = 0; mi < 2; ++mi)
#pragma unroll
      for (int reg = 0; reg < 4; ++reg) {
        float* row = outb + (size_t)(d0 + mi * 16 + laneg * 4 + reg) * HTT;
#pragma unroll
        for (int ni = 0; ni < 8; ++ni)
          row[ni * 16 + lanem] = ac[mi][ni][reg];
      }
  };

  float4 bufA[8], bufB[8];
  LOADC(0, bufA);
#pragma unroll
  for (int cc = 0; cc < 4; ++cc) {
    LOADC(cc * 64 + 32, bufB);
    COMP(cc * 64, bufA);
    if (cc < 3) LOADC(cc * 64 + 64, bufA);
    COMP(cc * 64 + 32, bufB);
  }
}

extern "C" void kernel_launch(void* const* d_in, const int* in_sizes, int n_in,
                              void* d_out, int out_size, void* d_ws, size_t ws_size,
                              hipStream_t stream) {
  const float* qk     = (const float*)d_in[0];
  const float* pd     = (const float*)d_in[1];
  const float* temb   = (const float*)d_in[2];
  const float* w_dist = (const float*)d_in[3];
  const float* b_dist = (const float*)d_in[4];
  const float* w_time = (const float*)d_in[5];
  const float* b_time = (const float*)d_in[6];
  const float* w_out  = (const float*)d_in[7];
  const float* b_out  = (const float*)d_in[8];
  float* out = (float*)d_out;

  char* ws = (char*)d_ws;
  float* base = (float*)(ws);              // 524288 B
  float* wd4  = (float*)(ws + 524288);     //   8192 B
  short* wsw  = (short*)(ws + 532480);     // 524288 B

  hipLaunchKernelGGL(k_prep, dim3(64), dim3(256), 0, stream,
                     w_out, w_dist, wsw, wd4);
  hipLaunchKernelGGL(k_base, dim3(8, 8), dim3(256), 0, stream,
                     temb, w_time, b_time, b_dist, base);
  hipLaunchKernelGGL(k_fused, dim3(B_ * T_), dim3(512), 0, stream,
                     qk, pd, base, wd4, wsw, b_out, out);
}